// Round 10
// baseline (203.914 us; speedup 1.0000x reference)
//
#include <hip/hip_runtime.h>

// out[b,d,t] = sum_c x[b,c,t] * weights[subjects[b],c,d]
// B=256, C=270, T=1024, NSUB=200. fp32 in/out, bf16 MFMA internally.
//
// DMA staging via global_load_lds into fp32 LDS tiles [c][t] / [c][d].
// B (x) staged at width 16 (always 16B-aligned: row stride 4KB, t-offsets
// multiples of 16B). A (w) staged at width 4: row stride 270 floats means
// odd-c rows are only 8B-aligned, and width-16 DMA from non-16B-aligned
// sources corrupts the transfer (round-9 failure, absmax 0.25 on odd-c
// slices). Width-4 is always aligned.
// Fragments built at consume: 8x ds_read_b32 + 4x v_cvt_pk_bf16_f32 per
// frag. k-order freedom: A and B both use c = 8*j + 2*lg + {0,1} (same
// bijection on both operands -> exact dot product). Tail tile clamps
// global addresses and zero-masks invalid B-frag slots.

#define C_    270
#define T_    1024
#define B_    256
#define NSUB_ 200

#define BM 64      // d-tile
#define BN 128     // t-tile
#define BK 32      // c-step
#define LB_U32 (BK * BN)            // 4096 u32 = 16 KB  [c][t] fp32
#define LA_U32 (BK * BM)            // 2048 u32 =  8 KB  [c][d] fp32
#define BUF_U32 (LB_U32 + LA_U32)   // 24 KB per buffer

typedef __attribute__((ext_vector_type(8))) short bf16x8;
typedef __attribute__((ext_vector_type(4))) float f32x4;
typedef __attribute__((ext_vector_type(4))) int i32x4;

__device__ __forceinline__ unsigned pk(float lo, float hi) {
    // v_cvt_pk_bf16_f32: RNE, lo -> low 16 bits. No builtin on gfx950.
    unsigned r;
    asm("v_cvt_pk_bf16_f32 %0, %1, %2" : "=v"(r) : "v"(lo), "v"(hi));
    return r;
}

// Async global->LDS. Dest = wave-uniform base + lane*width.
__device__ __forceinline__ void gl2lds16(const float* g, const unsigned* l) {
    __builtin_amdgcn_global_load_lds(
        (__attribute__((address_space(1))) void*)g,
        (__attribute__((address_space(3))) void*)l, 16, 0, 0);
}
__device__ __forceinline__ void gl2lds4(const float* g, const unsigned* l) {
    __builtin_amdgcn_global_load_lds(
        (__attribute__((address_space(1))) void*)g,
        (__attribute__((address_space(3))) void*)l, 4, 0, 0);
}

__global__ __launch_bounds__(256, 3)
void subj_layers_kernel(const float* __restrict__ x,
                        const int* __restrict__ subjects,
                        const float* __restrict__ w,
                        float* __restrict__ out)
{
    __shared__ unsigned lds[2][BUF_U32];

    const int tid  = threadIdx.x;
    const int lane = tid & 63;
    const int wid  = tid >> 6;
    const int wr   = wid >> 1;   // wave d-row 0..1 (32 d each)
    const int wc   = wid & 1;    // wave t-col 0..1 (64 t each)
    const int lg   = lane >> 4;
    const int lr   = lane & 15;
    const int l5   = lane >> 5, l31 = lane & 31;  // B staging split

    // Bijective XCD-chunk swizzle (10240 = 8 x 1280), d-tile fastest so the
    // 5 d-blocks sharing one x-slice are same-XCD and temporally adjacent.
    const int bid  = (blockIdx.x & 7) * 1280 + (blockIdx.x >> 3);
    const int b    = bid / 40;
    const int rem  = bid % 40;
    const int d0   = (rem % 5) * BM;   // 0,64,128,192,256
    const int t0   = (rem / 5) * BN;   // 0..896

    int sub = subjects[b];
    sub = sub < 0 ? 0 : (sub >= NSUB_ ? NSUB_ - 1 : sub);
    const float* __restrict__ wsub = w + (size_t)sub * (C_ * C_);
    const float* __restrict__ xb   = x + (size_t)b * (C_ * T_);
    const float* wLast = w + (size_t)NSUB_ * C_ * C_ - 1;  // last valid elem

    // ---- per-lane staging base pointers ----
    // B: instr i (0..15): lane -> global (c = c0+2i+l5, t = t0+4*l31), 16B.
    //    LDS dest: L + i*256 u32  => [c][128] rows.
    // A: instr i (0..31): lane -> global (c = c0+i, d = d0+lane), 4B.
    //    LDS dest: L + LB_U32 + i*64 u32 => [c][64] rows.
    const float* xg = xb + (size_t)l5 * T_ + t0 + 4 * l31;
    const float* ag = wsub + d0 + lane;

    auto stage_full = [&](unsigned* L, int c0) {
        #pragma unroll
        for (int ii = 0; ii < 4; ++ii) {
            const int i = wid + 4 * ii;
            gl2lds16(xg + (size_t)(c0 + 2 * i) * T_, L + i * 256);
        }
        #pragma unroll
        for (int ii = 0; ii < 8; ++ii) {
            const int i = wid + 4 * ii;
            gl2lds4(ag + (size_t)(c0 + i) * C_, L + LB_U32 + i * 64);
        }
    };

    // Tail tile (c0=256): clamp c to 269 (finite data; invalid k-slots are
    // zero-masked on the B side at consume), clamp A's address into w.
    auto stage_tail = [&](unsigned* L) {
        #pragma unroll
        for (int ii = 0; ii < 4; ++ii) {
            const int i = wid + 4 * ii;
            int c = 256 + 2 * i + l5; c = c < C_ ? c : C_ - 1;
            gl2lds16(xb + (size_t)c * T_ + t0 + 4 * l31, L + i * 256);
        }
        #pragma unroll
        for (int ii = 0; ii < 8; ++ii) {
            const int i = wid + 4 * ii;
            int c = 256 + i; c = c < C_ ? c : C_ - 1;
            const float* ga = ag + (size_t)c * C_;
            if (ga > wLast) ga = wLast;
            gl2lds4(ga, L + LB_U32 + i * 64);
        }
    };

    f32x4 acc[2][4];
    #pragma unroll
    for (int m = 0; m < 2; ++m)
        #pragma unroll
        for (int n = 0; n < 4; ++n)
            acc[m][n] = (f32x4){0.f, 0.f, 0.f, 0.f};

    // Fragment build: slot j (u32) = pk(v[c=8j+2lg], v[c=8j+2lg+1]).
    // Same k-permutation for A and B -> exact dot product over c=0..31.
    auto compute = [&](const unsigned* L, bool tail) {
        const float* Bt = (const float*)L;             // [32][128]
        const float* At = (const float*)(L + LB_U32);  // [32][64]
        const int crel = 2 * lg;
        bf16x8 af[2], bfr[4];
        #pragma unroll
        for (int m = 0; m < 2; ++m) {
            const float* p = At + (size_t)crel * BM + (wr * 32 + m * 16 + lr);
            i32x4 u;
            #pragma unroll
            for (int j = 0; j < 4; ++j)
                u[j] = (int)pk(p[j * 8 * BM], p[j * 8 * BM + BM]);
            af[m] = __builtin_bit_cast(bf16x8, u);
        }
        #pragma unroll
        for (int n = 0; n < 4; ++n) {
            const float* p = Bt + (size_t)crel * BN + (wc * 64 + n * 16 + lr);
            i32x4 u;
            #pragma unroll
            for (int j = 0; j < 4; ++j)
                u[j] = (int)pk(p[j * 8 * BN], p[j * 8 * BN + BN]);
            if (tail) {                 // c = 256 + 8j + 2lg + {0,1}
                u[2] = 0; u[3] = 0;     // c >= 272: invalid
                if (lg == 3) u[1] = 0;  // c = 270,271: invalid
            }
            bfr[n] = __builtin_bit_cast(bf16x8, u);
        }
        #pragma unroll
        for (int m = 0; m < 2; ++m)
            #pragma unroll
            for (int n = 0; n < 4; ++n)
                acc[m][n] = __builtin_amdgcn_mfma_f32_16x16x32_bf16(af[m], bfr[n], acc[m][n], 0, 0, 0);
    };

    // ---- pipeline: issue tile k+1 DMA, compute tile k; __syncthreads
    // drains vmcnt (tile k+1 resident) and protects buffers. ----
    stage_full(&lds[0][0], 0);
    __syncthreads();

    #pragma unroll 1
    for (int k = 0; k < 7; ++k) {
        stage_full(&lds[(k + 1) & 1][0], (k + 1) * BK);  // tiles 1..7
        compute(&lds[k & 1][0], false);                  // tiles 0..6
        __syncthreads();
    }
    stage_tail(&lds[0][0]);                 // tile 8 -> buf0
    compute(&lds[1][0], false);             // tile 7
    __syncthreads();
    compute(&lds[0][0], true);              // tile 8 (masked)

    // ---- epilogue: C/D layout col=lane&15, row=(lane>>4)*4+reg ----
    float* outb = out + (size_t)b * (C_ * T_);
    #pragma unroll
    for (int m = 0; m < 2; ++m) {
        const int dbase = d0 + wr * 32 + m * 16 + 4 * lg;
        #pragma unroll
        for (int n = 0; n < 4; ++n) {
            const int t = t0 + wc * 64 + n * 16 + lr;
            #pragma unroll
            for (int rr = 0; rr < 4; ++rr) {
                const int d = dbase + rr;
                if (d < C_)
                    outb[(size_t)d * T_ + t] = acc[m][n][rr];
            }
        }
    }
}

extern "C" void kernel_launch(void* const* d_in, const int* in_sizes, int n_in,
                              void* d_out, int out_size, void* d_ws, size_t ws_size,
                              hipStream_t stream)
{
    const float* x        = (const float*)d_in[0];
    const int*   subjects = (const int*)d_in[1];
    const float* w        = (const float*)d_in[2];
    float* out            = (float*)d_out;

    dim3 grid(B_ * 40);  // 256 batches * (5 d-tiles * 8 t-tiles) = 10240
    dim3 block(256);
    hipLaunchKernelGGL(subj_layers_kernel, grid, block, 0, stream,
                       x, subjects, w, out);
}

// Round 11
// 202.468 us; speedup vs baseline: 1.0071x; 1.0071x over previous
//
#include <hip/hip_runtime.h>

// out[b,d,t] = sum_c x[b,c,t] * weights[subjects[b],c,d]
// B=256, C=270, T=1024, NSUB=200. fp32 in/out, bf16 MFMA internally.
//
// DMA staging (global_load_lds) of fp32 tiles into LDS; fragments built at
// consume with scalar ds_read_b32 + v_cvt_pk_bf16_f32.
// R11 change: PADDED LDS strides. R10's linear layouts had row strides
// 128/64 u32 (both = 0 mod 32 banks), so all 4 lane-groups of a frag read
// aliased onto the same 16 banks -> 4-way conflict on all 48 reads/wave-step
// (SQ_LDS_BANK_CONFLICT 3.4e7; LDS pipe = the wall). Padding is applied at
// DMA-instruction granularity (dest stays contiguous per instruction):
//   B: row-pair stride 256 -> 264 u32   (banks: 8*lg + t  -> 2-way, free)
//   A: row stride        64 -> 72  u32  (banks: 16*lg+8b+d -> 2-way, free)
// k-order freedom: A and B frags both use c = 8*j + 2*lg + {0,1}; tail tile
// clamps global addresses and zero-masks invalid B-frag k-slots.

#define C_    270
#define T_    1024
#define B_    256
#define NSUB_ 200

#define BM 64        // d-tile
#define BN 128       // t-tile
#define BK 32        // c-step
#define RPB 264      // u32 stride of one c-row-PAIR of B (256 data + 8 pad)
#define RA  72       // u32 stride of one c-row of A (64 data + 8 pad)
#define LB_U32 (16 * RPB)           // 4224 u32  [c/2][2][128+pad] fp32
#define LA_U32 (32 * RA)            // 2304 u32  [c][64+pad] fp32
#define BUF_U32 (LB_U32 + LA_U32)   // 6528 u32 = 26112 B per buffer

typedef __attribute__((ext_vector_type(8))) short bf16x8;
typedef __attribute__((ext_vector_type(4))) float f32x4;
typedef __attribute__((ext_vector_type(4))) int i32x4;

__device__ __forceinline__ unsigned pk(float lo, float hi) {
    // v_cvt_pk_bf16_f32: RNE, lo -> low 16 bits. No builtin on gfx950.
    unsigned r;
    asm("v_cvt_pk_bf16_f32 %0, %1, %2" : "=v"(r) : "v"(lo), "v"(hi));
    return r;
}

// Async global->LDS. Dest = wave-uniform base + lane*width.
__device__ __forceinline__ void gl2lds16(const float* g, const unsigned* l) {
    __builtin_amdgcn_global_load_lds(
        (__attribute__((address_space(1))) void*)g,
        (__attribute__((address_space(3))) void*)l, 16, 0, 0);
}
__device__ __forceinline__ void gl2lds4(const float* g, const unsigned* l) {
    __builtin_amdgcn_global_load_lds(
        (__attribute__((address_space(1))) void*)g,
        (__attribute__((address_space(3))) void*)l, 4, 0, 0);
}

__global__ __launch_bounds__(256, 3)
void subj_layers_kernel(const float* __restrict__ x,
                        const int* __restrict__ subjects,
                        const float* __restrict__ w,
                        float* __restrict__ out)
{
    __shared__ unsigned lds[2][BUF_U32];

    const int tid  = threadIdx.x;
    const int lane = tid & 63;
    const int wid  = tid >> 6;
    const int wr   = wid >> 1;   // wave d-row 0..1 (32 d each)
    const int wc   = wid & 1;    // wave t-col 0..1 (64 t each)
    const int lg   = lane >> 4;
    const int lr   = lane & 15;
    const int l5   = lane >> 5, l31 = lane & 31;  // B staging split

    // Bijective XCD-chunk swizzle (10240 = 8 x 1280), d-tile fastest so the
    // 5 d-blocks sharing one x-slice are same-XCD and temporally adjacent.
    const int bid  = (blockIdx.x & 7) * 1280 + (blockIdx.x >> 3);
    const int b    = bid / 40;
    const int rem  = bid % 40;
    const int d0   = (rem % 5) * BM;   // 0,64,128,192,256
    const int t0   = (rem / 5) * BN;   // 0..896

    int sub = subjects[b];
    sub = sub < 0 ? 0 : (sub >= NSUB_ ? NSUB_ - 1 : sub);
    const float* __restrict__ wsub = w + (size_t)sub * (C_ * C_);
    const float* __restrict__ xb   = x + (size_t)b * (C_ * T_);
    const float* wLast = w + (size_t)NSUB_ * C_ * C_ - 1;  // last valid elem

    // ---- per-lane staging base pointers ----
    // B: instr i (0..15): lane -> global (c = c0+2i+l5, t = t0+4*l31), 16B.
    //    LDS dest: L + i*RPB u32 (1056B regions; contiguous 1KB per instr).
    // A: instr i (0..31): lane -> global (c = c0+i, d = d0+lane), 4B.
    //    LDS dest: L + LB_U32 + i*RA u32 (288B regions; contiguous 256B).
    const float* xg = xb + (size_t)l5 * T_ + t0 + 4 * l31;
    const float* ag = wsub + d0 + lane;

    auto stage_full = [&](unsigned* L, int c0) {
        #pragma unroll
        for (int ii = 0; ii < 4; ++ii) {
            const int i = wid + 4 * ii;
            gl2lds16(xg + (size_t)(c0 + 2 * i) * T_, L + i * RPB);
        }
        #pragma unroll
        for (int ii = 0; ii < 8; ++ii) {
            const int i = wid + 4 * ii;
            gl2lds4(ag + (size_t)(c0 + i) * C_, L + LB_U32 + i * RA);
        }
    };

    // Tail tile (c0=256): clamp c to 269 (finite data; invalid k-slots are
    // zero-masked on the B side at consume), clamp A's address into w.
    auto stage_tail = [&](unsigned* L) {
        #pragma unroll
        for (int ii = 0; ii < 4; ++ii) {
            const int i = wid + 4 * ii;
            int c = 256 + 2 * i + l5; c = c < C_ ? c : C_ - 1;
            gl2lds16(xb + (size_t)c * T_ + t0 + 4 * l31, L + i * RPB);
        }
        #pragma unroll
        for (int ii = 0; ii < 8; ++ii) {
            const int i = wid + 4 * ii;
            int c = 256 + i; c = c < C_ ? c : C_ - 1;
            const float* ga = ag + (size_t)c * C_;
            if (ga > wLast) ga = wLast;
            gl2lds4(ga, L + LB_U32 + i * RA);
        }
    };

    f32x4 acc[2][4];
    #pragma unroll
    for (int m = 0; m < 2; ++m)
        #pragma unroll
        for (int n = 0; n < 4; ++n)
            acc[m][n] = (f32x4){0.f, 0.f, 0.f, 0.f};

    // Fragment build: slot j (u32) = pk(v[c=8j+2lg], v[c=8j+2lg+1]).
    // Same k-permutation for A and B -> exact dot product over c=0..31.
    // B element (c,t) at u32 (c>>1)*RPB + (c&1)*128 + t;
    // A element (c,d) at u32 c*RA + d.
    auto compute = [&](const unsigned* L, bool tail) {
        const float* Bt = (const float*)L;
        const float* At = (const float*)(L + LB_U32);
        bf16x8 af[2], bfr[4];
        #pragma unroll
        for (int m = 0; m < 2; ++m) {
            // c = 8j+2lg+{0,1}: addr = (8j+2lg+b)*RA + d
            const float* p = At + (size_t)(2 * lg) * RA + (wr * 32 + m * 16 + lr);
            i32x4 u;
            #pragma unroll
            for (int j = 0; j < 4; ++j)
                u[j] = (int)pk(p[j * 8 * RA], p[j * 8 * RA + RA]);
            af[m] = __builtin_bit_cast(bf16x8, u);
        }
        #pragma unroll
        for (int n = 0; n < 4; ++n) {
            // c = 8j+2lg+{0,1}: pair index 4j+lg, beta = c&1 -> +128
            const float* p = Bt + (size_t)lg * RPB + (wc * 64 + n * 16 + lr);
            i32x4 u;
            #pragma unroll
            for (int j = 0; j < 4; ++j)
                u[j] = (int)pk(p[j * 4 * RPB], p[j * 4 * RPB + 128]);
            if (tail) {                 // c = 256 + 8j + 2lg + {0,1}
                u[2] = 0; u[3] = 0;     // c >= 272: invalid
                if (lg == 3) u[1] = 0;  // c = 270,271: invalid
            }
            bfr[n] = __builtin_bit_cast(bf16x8, u);
        }
        #pragma unroll
        for (int m = 0; m < 2; ++m)
            #pragma unroll
            for (int n = 0; n < 4; ++n)
                acc[m][n] = __builtin_amdgcn_mfma_f32_16x16x32_bf16(af[m], bfr[n], acc[m][n], 0, 0, 0);
    };

    // ---- pipeline: issue tile k+1 DMA, compute tile k; __syncthreads
    // drains vmcnt (tile k+1 resident) and protects buffers. ----
    stage_full(&lds[0][0], 0);
    __syncthreads();

    #pragma unroll 1
    for (int k = 0; k < 7; ++k) {
        stage_full(&lds[(k + 1) & 1][0], (k + 1) * BK);  // tiles 1..7
        compute(&lds[k & 1][0], false);                  // tiles 0..6
        __syncthreads();
    }
    stage_tail(&lds[0][0]);                 // tile 8 -> buf0
    compute(&lds[1][0], false);             // tile 7
    __syncthreads();
    compute(&lds[0][0], true);              // tile 8 (masked)

    // ---- epilogue: C/D layout col=lane&15, row=(lane>>4)*4+reg ----
    float* outb = out + (size_t)b * (C_ * T_);
    #pragma unroll
    for (int m = 0; m < 2; ++m) {
        const int dbase = d0 + wr * 32 + m * 16 + 4 * lg;
        #pragma unroll
        for (int n = 0; n < 4; ++n) {
            const int t = t0 + wc * 64 + n * 16 + lr;
            #pragma unroll
            for (int rr = 0; rr < 4; ++rr) {
                const int d = dbase + rr;
                if (d < C_)
                    outb[(size_t)d * T_ + t] = acc[m][n][rr];
            }
        }
    }
}

extern "C" void kernel_launch(void* const* d_in, const int* in_sizes, int n_in,
                              void* d_out, int out_size, void* d_ws, size_t ws_size,
                              hipStream_t stream)
{
    const float* x        = (const float*)d_in[0];
    const int*   subjects = (const int*)d_in[1];
    const float* w        = (const float*)d_in[2];
    float* out            = (float*)d_out;

    dim3 grid(B_ * 40);  // 256 batches * (5 d-tiles * 8 t-tiles) = 10240
    dim3 block(256);
    hipLaunchKernelGGL(subj_layers_kernel, grid, block, 0, stream,
                       x, subjects, w, out);
}